// Round 1
// baseline (12.139 us; speedup 1.0000x reference)
//
#include <hip/hip_runtime.h>

#define BN_EPS 1e-3f

// Kernel 1: per-node partial sums.
// S_i[b*N+n] = sum_f relu(feat[b,n,f]*inv[1+f]   + bias[1+f])   * w[1+f]
// S_j[b*N+n] = sum_f relu(feat[b,n,f]*inv[1+F+f] + bias[1+F+f]) * w[1+F+f]
// One wave (64 threads) per (b,n) row; F == 64 in this problem.
__global__ void node_sums_kernel(const float* __restrict__ feat,   // [B,N,F]
                                 const float* __restrict__ gamma,
                                 const float* __restrict__ beta,
                                 const float* __restrict__ mean,
                                 const float* __restrict__ var,
                                 const float* __restrict__ w,
                                 float* __restrict__ Si,
                                 float* __restrict__ Sj,
                                 int F) {
    const int row = blockIdx.x;          // b*N + n
    const int f   = threadIdx.x;         // 0..F-1
    const float x = feat[(long long)row * F + f];

    const int ci = 1 + f;
    const int cj = 1 + F + f;

    const float invi = gamma[ci] * rsqrtf(var[ci] + BN_EPS);
    const float bi   = beta[ci] - mean[ci] * invi;
    const float invj = gamma[cj] * rsqrtf(var[cj] + BN_EPS);
    const float bj   = beta[cj] - mean[cj] * invj;

    float vi = fmaxf(fmaf(x, invi, bi), 0.0f) * w[ci];
    float vj = fmaxf(fmaf(x, invj, bj), 0.0f) * w[cj];

    // wave64 butterfly reduce
    #pragma unroll
    for (int off = 32; off > 0; off >>= 1) {
        vi += __shfl_down(vi, off, 64);
        vj += __shfl_down(vj, off, 64);
    }
    if (f == 0) {
        Si[row] = vi;
        Sj[row] = vj;
    }
}

// Kernel 2: out[b,i,j] = relu(adj*inv0 + bias0)*w0 + Si[b*N+i] + Sj[b*N+j] + cb
// float4 over the flat [B*N*N] adjacency; N % 4 == 0 so a float4 stays in one row.
__global__ void out_kernel(const float* __restrict__ adj,
                           const float* __restrict__ Si,
                           const float* __restrict__ Sj,
                           float* __restrict__ out,
                           const float* __restrict__ gamma,
                           const float* __restrict__ beta,
                           const float* __restrict__ mean,
                           const float* __restrict__ var,
                           const float* __restrict__ w,
                           const float* __restrict__ conv_b,
                           int N, int total4) {
    const int t = blockIdx.x * blockDim.x + threadIdx.x;
    if (t >= total4) return;

    // channel-0 params: uniform address -> scalar loads, cached
    const float inv0 = gamma[0] * rsqrtf(var[0] + BN_EPS);
    const float b0   = beta[0] - mean[0] * inv0;
    const float w0   = w[0];
    const float cb   = conv_b[0];

    const float4 a = reinterpret_cast<const float4*>(adj)[t];

    const int idx = t * 4;              // flat index into [B*N*N]
    const int row = idx / N;            // b*N + i
    const int b   = row / N;            // batch
    const int j0  = idx - row * N;

    const float si = Si[row] + cb;
    const float* sjp = Sj + b * N + j0;

    float4 r;
    r.x = fmaxf(fmaf(a.x, inv0, b0), 0.0f) * w0 + si + sjp[0];
    r.y = fmaxf(fmaf(a.y, inv0, b0), 0.0f) * w0 + si + sjp[1];
    r.z = fmaxf(fmaf(a.z, inv0, b0), 0.0f) * w0 + si + sjp[2];
    r.w = fmaxf(fmaf(a.w, inv0, b0), 0.0f) * w0 + si + sjp[3];

    reinterpret_cast<float4*>(out)[t] = r;
}

extern "C" void kernel_launch(void* const* d_in, const int* in_sizes, int n_in,
                              void* d_out, int out_size, void* d_ws, size_t ws_size,
                              hipStream_t stream) {
    const float* feat  = (const float*)d_in[0];   // [B,N,F]
    const float* adj   = (const float*)d_in[1];   // [B,N,N]
    const float* gamma = (const float*)d_in[2];   // [C]
    const float* beta  = (const float*)d_in[3];
    const float* mean  = (const float*)d_in[4];
    const float* var   = (const float*)d_in[5];
    const float* w     = (const float*)d_in[6];
    const float* cb    = (const float*)d_in[7];   // [1]

    const int C  = in_sizes[2];
    const int F  = (C - 1) / 2;                   // 64
    const int BN = in_sizes[0] / F;               // B*N = 2048
    const long long total = in_sizes[1];          // B*N*N
    const int N  = (int)(total / BN);             // 512

    float* Si = (float*)d_ws;                     // BN floats
    float* Sj = Si + BN;                          // BN floats

    node_sums_kernel<<<BN, F, 0, stream>>>(feat, gamma, beta, mean, var, w, Si, Sj, F);

    const int total4  = (int)(total / 4);
    const int threads = 256;
    const int blocks  = (total4 + threads - 1) / threads;
    out_kernel<<<blocks, threads, 0, stream>>>(adj, Si, Sj, (float*)d_out,
                                               gamma, beta, mean, var, w, cb,
                                               N, total4);
}